// Round 8
// baseline (207.606 us; speedup 1.0000x reference)
//
#include <hip/hip_runtime.h>
#include <math.h>

// Problem constants (match reference setup_inputs)
#define Bn 4096
#define Sn 2048
#define BLOCK 256                // 4 waves/block; ONE WAVE OWNS ONE SEQUENCE
#define NTILE 16                 // 2048 steps = 16 tiles x 128 steps (2/lane)

// =====================================================================
// Round 8: barrier-free autonomous-wave streamer (copy-kernel shape).
// R0-R7 invariance: ~74us across VALU weight, coalescing, load mechanism,
// occupancy, fused/split -- all shared barrier-synchronized load bursts.
// Here each wave streams its own sequence end-to-end: continuous load
// issue (rotating 1-tile prefetch), shuffle-only reduction, no barriers
// after init, no workspace. Math = validated R2 linear-domain scan +
// R7 normalized butterfly (absmax 8.0 every round).
// =====================================================================
__global__ __launch_bounds__(BLOCK, 4) void crf_wave(
    const float* __restrict__ emissions,     // [B, S, 2]
    const float* __restrict__ trans_params,  // [4, 2, 2]
    const int*   __restrict__ tags,          // [B, S]
    const int*   __restrict__ who2who,       // [B, S]
    const int*   __restrict__ intime,        // [B, S]
    const int*   __restrict__ distance,      // [B, S]
    float*       __restrict__ out)           // [2, B]
{
    const int lane = threadIdx.x & 63;
    const int g    = blockIdx.x * 4 + (threadIdx.x >> 6);   // sequence id
    const long base = (long)g * Sn;

    // sel banks: [sel][i][j] at [sel*4+i*2+j]; sel==0 is zero/ones matrix
    __shared__ __align__(16) float lbank[20];   // log-domain (gold)
    __shared__ __align__(16) float ebank[20];   // exp(trans)  (scan)
    if (threadIdx.x < 20) {
        float v = (threadIdx.x < 4) ? 0.0f : trans_params[threadIdx.x - 4];
        lbank[threadIdx.x] = v;
        ebank[threadIdx.x] = __expf(v);
    }
    __syncthreads();            // ONLY barrier (init, before steady state)

    const float4* ep = (const float4*)(emissions + base * 2); // [1024]
    const int2*   tp = (const int2*)(tags     + base);        // [1024]
    const int2*   wp = (const int2*)(who2who  + base);
    const int2*   ip = (const int2*)(intime   + base);
    const int2*   dp = (const int2*)(distance + base);

    // prefetch tile 0 (lane-dense: one 1KB / four 512B wave transactions)
    float4 e  = ep[lane];
    int2   tg = tp[lane], wh = wp[lane], it = ip[lane], ds = dp[lane];

    float r00 = 1.f, r01 = 0.f, r10 = 0.f, r11 = 0.f; // running product
    float Luni  = 0.0f;   // wave-uniform log-scale (R renorms)
    float Llane = 0.0f;   // per-lane log-scale partial (reduced at end)
    float gold  = 0.0f;   // per-lane gold partial     (reduced at end)
    int carry_tag = 0;    // last tag of previous tile (wave-uniform)

    for (int i = 0; i < NTILE; ++i) {
        // ---- rotating prefetch: next tile's 5 loads issue before compute
        float4 e_n; int2 tg_n, wh_n, it_n, ds_n;
        if (i + 1 < NTILE) {
            int o = (i + 1) * 64 + lane;
            e_n = ep[o]; tg_n = tp[o]; wh_n = wp[o];
            it_n = ip[o]; ds_n = dp[o];
        }

        // ---- per-lane 2-step matrix (linear domain) ----
        int sel0 = (wh.x == -1) ? 0 : (wh.x == 1) ? 1
                 : (it.x == 0) ? 2 : (ds.x == 0) ? 3 : 4;
        int sel1 = (wh.y == -1) ? 0 : (wh.y == 1) ? 1
                 : (it.y == 0) ? 2 : (ds.y == 0) ? 3 : 4;
        float4 P0 = *(const float4*)(ebank + sel0 * 4);
        float4 P1 = *(const float4*)(ebank + sel1 * 4);
        float x00 = __expf(e.x), x01 = __expf(e.y);
        float x10 = __expf(e.z), x11 = __expf(e.w);
        float a00 = P0.x * x00, a01 = P0.y * x01;
        float a10 = P0.z * x00, a11 = P0.w * x01;
        float b00 = P1.x * x10, b01 = P1.y * x11;
        float b10 = P1.z * x10, b11 = P1.w * x11;
        float m00 = fmaf(a00, b00, a01 * b10);
        float m01 = fmaf(a00, b01, a01 * b11);
        float m10 = fmaf(a10, b00, a11 * b10);
        float m11 = fmaf(a10, b01, a11 * b11);

        // ---- gold partial (log domain) ----
        gold += (tg.x ? e.y : e.x) + (tg.y ? e.w : e.z);
        int pt0 = __shfl_up(tg.y, 1);
        if (lane == 0) pt0 = carry_tag;
        if (i > 0 || lane > 0)               // sequence start: no transition
            gold += lbank[(sel0 << 2) + (pt0 << 1) + tg.x];
        gold += lbank[(sel1 << 2) + (tg.x << 1) + tg.y];
        carry_tag = __shfl(tg.y, 63);

        // ---- normalize lane matrix; log into per-lane partial ----
        float mx  = fmaxf(fmaxf(m00, m01), fmaxf(m10, m11));
        float inv = 1.0f / mx;
        Llane += __logf(mx);
        m00 *= inv; m01 *= inv; m10 *= inv; m11 *= inv;

        // ---- ordered 64-lane butterfly (4 shuffles/round; R7-validated)
        #pragma unroll
        for (int m = 1; m < 64; m <<= 1) {
            float o00 = __shfl_xor(m00, m);
            float o01 = __shfl_xor(m01, m);
            float o10 = __shfl_xor(m10, m);
            float o11 = __shfl_xor(m11, m);
            bool up = (lane & m) != 0;
            float p00 = up ? o00 : m00, p01 = up ? o01 : m01;
            float p10 = up ? o10 : m10, p11 = up ? o11 : m11;
            float q00 = up ? m00 : o00, q01 = up ? m01 : o01;
            float q10 = up ? m10 : o10, q11 = up ? m11 : o11;
            m00 = fmaf(p00, q00, p01 * q10);
            m01 = fmaf(p00, q01, p01 * q11);
            m10 = fmaf(p10, q00, p11 * q10);
            m11 = fmaf(p10, q01, p11 * q11);
        }

        // ---- compose running product R = R (then) T; renorm ----
        if (i == 0) {
            r00 = m00; r01 = m01; r10 = m10; r11 = m11;
        } else {
            float n00 = fmaf(r00, m00, r01 * m10);
            float n01 = fmaf(r00, m01, r01 * m11);
            float n10 = fmaf(r10, m00, r11 * m10);
            float n11 = fmaf(r10, m01, r11 * m11);
            r00 = n00; r01 = n01; r10 = n10; r11 = n11;
        }
        float mx2  = fmaxf(fmaxf(r00, r01), fmaxf(r10, r11));
        float inv2 = 1.0f / mx2;
        Luni += __logf(mx2);
        r00 *= inv2; r01 *= inv2; r10 *= inv2; r11 *= inv2;

        // rotate prefetch buffers
        e = e_n; tg = tg_n; wh = wh_n; it = it_n; ds = ds_n;
    }

    // ---- final additive reductions (shuffle-only) ----
    #pragma unroll
    for (int m = 1; m < 64; m <<= 1) {
        gold  += __shfl_xor(gold, m);
        Llane += __shfl_xor(Llane, m);
    }

    if (lane == 0) {
        // total = scale + log(sum of entries)   (alpha0 = zeros)
        float tot = Luni + Llane + __logf(r00 + r01 + r10 + r11);
        out[g]      = gold;   // gold_score
        out[Bn + g] = tot;    // total_score
    }
}

extern "C" void kernel_launch(void* const* d_in, const int* in_sizes, int n_in,
                              void* d_out, int out_size, void* d_ws, size_t ws_size,
                              hipStream_t stream) {
    const float* emissions    = (const float*)d_in[0];
    const float* trans_params = (const float*)d_in[1];
    const int*   tags         = (const int*)d_in[2];
    const int*   who2who      = (const int*)d_in[3];
    const int*   intime       = (const int*)d_in[4];
    const int*   distance     = (const int*)d_in[5];
    float* out = (float*)d_out;

    crf_wave<<<dim3(Bn / 4), dim3(BLOCK), 0, stream>>>(
        emissions, trans_params, tags, who2who, intime, distance, out);
}

// Round 9
// 201.251 us; speedup vs baseline: 1.0316x; 1.0316x over previous
//
#include <hip/hip_runtime.h>
#include <math.h>

// Problem constants (match reference setup_inputs)
#define Bn 4096
#define Sn 2048
#define NPAIR (Bn * (Sn / 2))        // 4,194,304 2-step pairs
#define K1B 256
#define K1G (NPAIR / K1B)            // 16384 blocks
#define NGRP 64                      // 32-step groups per sequence

// bf16 round-to-nearest pack of two floats: x -> low16, y -> high16
__device__ __forceinline__ unsigned pack_bf16(float x, float y) {
    unsigned bx = __float_as_uint(x);
    unsigned by = __float_as_uint(y);
    bx += 0x7FFFu + ((bx >> 16) & 1);
    by += 0x7FFFu + ((by >> 16) & 1);
    return (bx >> 16) | (by & 0xFFFF0000u);
}

// =====================================================================
// Kernel 1: m13-copy-shaped streamer. NO LDS, NO barriers, no block
// coupling. Thread = one 2-step pair (all loads lane-dense). Dependent
// chain after data arrival: ~8 exp + 12 fma + 4 shuffle-rounds (~500cy).
// R0-R8 post-mortem: every prior shape kept loads outstanding only in
// short synchronized bursts (-> ~2.7 TB/s logical ceiling via Little's
// law, invariant to data residency). Here waves are fully independent;
// at ~32 resident waves/CU a large fraction sit in their load phase at
// any instant.
// =====================================================================
__global__ __launch_bounds__(K1B) void crf_stage(
    const float* __restrict__ emissions,     // [B, S, 2]
    const float* __restrict__ trans_params,  // [4, 2, 2]
    const int*   __restrict__ tags,          // [B, S]
    const int*   __restrict__ who2who,       // [B, S]
    const int*   __restrict__ intime,        // [B, S]
    const int*   __restrict__ distance,      // [B, S]
    float4*      __restrict__ ws)            // [Bn*NGRP] group records
{
    const int t    = blockIdx.x * K1B + threadIdx.x;  // global pair id
    const int lane = threadIdx.x & 63;
    const int j    = t & 1023;               // pair index within sequence

    // ---- dense coalesced loads (one vector instr each, lane-contiguous)
    float4 e  = ((const float4*)emissions)[t];   // steps 2j, 2j+1
    int2   tg = ((const int2*)tags)[t];
    int2   wh = ((const int2*)who2who)[t];
    int2   i2 = ((const int2*)intime)[t];
    int2   d2 = ((const int2*)distance)[t];
    int ptag = 0;
    if (lane == 0 && j != 0) ptag = tags[2 * t - 1];  // L1-hot line

    // ---- transition rows straight from global (80B, permanently L1-hot)
    int sel0 = (wh.x == -1) ? -1 : (wh.x == 1) ? 0
             : (i2.x == 0) ? 1 : (d2.x == 0) ? 2 : 3;
    int sel1 = (wh.y == -1) ? -1 : (wh.y == 1) ? 0
             : (i2.y == 0) ? 1 : (d2.y == 0) ? 2 : 3;
    float4 T0 = ((const float4*)trans_params)[sel0 < 0 ? 0 : sel0];
    float4 T1 = ((const float4*)trans_params)[sel1 < 0 ? 0 : sel1];
    if (sel0 < 0) T0 = make_float4(0.f, 0.f, 0.f, 0.f);  // w==-1: zero row
    if (sel1 < 0) T1 = make_float4(0.f, 0.f, 0.f, 0.f);

    // ---- 2-step matrix, fused exp(tr+em) (linear domain; validated R2+)
    float a00 = __expf(T0.x + e.x), a01 = __expf(T0.y + e.y);
    float a10 = __expf(T0.z + e.x), a11 = __expf(T0.w + e.y);
    float c00 = __expf(T1.x + e.z), c01 = __expf(T1.y + e.w);
    float c10 = __expf(T1.z + e.z), c11 = __expf(T1.w + e.w);
    float m00 = fmaf(a00, c00, a01 * c10);
    float m01 = fmaf(a00, c01, a01 * c11);
    float m10 = fmaf(a10, c00, a11 * c10);
    float m11 = fmaf(a10, c01, a11 * c11);

    // ---- gold partial (log domain; transitions owned by this pair)
    float gold = (tg.x ? e.y : e.x) + (tg.y ? e.w : e.z);
    int pt0 = __shfl_up(tg.y, 1);
    if (lane == 0) pt0 = ptag;
    if (j > 0)     // no transition at sequence start
        gold += pt0 ? (tg.x ? T0.w : T0.z) : (tg.x ? T0.y : T0.x);
    gold += tg.x ? (tg.y ? T1.w : T1.z) : (tg.y ? T1.y : T1.x);

    // ---- normalize; 4-round ordered butterfly -> 16-pair (32-step) group
    float mx  = fmaxf(fmaxf(m00, m01), fmaxf(m10, m11));
    float inv = 1.0f / mx;
    float L   = __logf(mx);
    m00 *= inv; m01 *= inv; m10 *= inv; m11 *= inv;

    #pragma unroll
    for (int m = 1; m < 16; m <<= 1) {   // growth <= 2^4 (no renorm needed)
        float o00 = __shfl_xor(m00, m);
        float o01 = __shfl_xor(m01, m);
        float o10 = __shfl_xor(m10, m);
        float o11 = __shfl_xor(m11, m);
        float oL  = __shfl_xor(L, m);
        float og  = __shfl_xor(gold, m);
        bool up = (lane & m) != 0;
        float p00 = up ? o00 : m00, p01 = up ? o01 : m01;
        float p10 = up ? o10 : m10, p11 = up ? o11 : m11;
        float q00 = up ? m00 : o00, q01 = up ? m01 : o01;
        float q10 = up ? m10 : o10, q11 = up ? m11 : o11;
        m00 = fmaf(p00, q00, p01 * q10);
        m01 = fmaf(p00, q01, p01 * q11);
        m10 = fmaf(p10, q00, p11 * q10);
        m11 = fmaf(p10, q01, p11 * q11);
        L += oL;
        gold += og;
    }

    // ---- group leader stores 16B record (4 leaders/wave, contiguous 64B)
    if ((lane & 15) == 0) {
        float mx2  = fmaxf(fmaxf(m00, m01), fmaxf(m10, m11));
        float inv2 = 1.0f / mx2;
        L += __logf(mx2);
        unsigned u01 = pack_bf16(m00 * inv2, m01 * inv2);
        unsigned u23 = pack_bf16(m10 * inv2, m11 * inv2);
        ws[t >> 4] = make_float4(__uint_as_float(u01), __uint_as_float(u23),
                                 L, gold);
    }
}

// =====================================================================
// Kernel 2: one wave per sequence. One dense 16B/lane load of the 64
// group records, one 6-round ordered butterfly, write [2,B] outputs.
// =====================================================================
__global__ __launch_bounds__(256) void crf_final(
    const float4* __restrict__ ws,
    float*        __restrict__ out)          // [2, B]
{
    const int lane = threadIdx.x & 63;
    const int b    = blockIdx.x * 4 + (threadIdx.x >> 6);

    float4 r = ws[b * NGRP + lane];
    unsigned u01 = __float_as_uint(r.x), u23 = __float_as_uint(r.y);
    float m00 = __uint_as_float(u01 << 16);
    float m01 = __uint_as_float(u01 & 0xFFFF0000u);
    float m10 = __uint_as_float(u23 << 16);
    float m11 = __uint_as_float(u23 & 0xFFFF0000u);
    float L = r.z, gold = r.w;

    #pragma unroll
    for (int m = 1; m < 64; m <<= 1) {   // inputs normalized: growth <= 64
        float o00 = __shfl_xor(m00, m);
        float o01 = __shfl_xor(m01, m);
        float o10 = __shfl_xor(m10, m);
        float o11 = __shfl_xor(m11, m);
        float oL  = __shfl_xor(L, m);
        float og  = __shfl_xor(gold, m);
        bool up = (lane & m) != 0;
        float p00 = up ? o00 : m00, p01 = up ? o01 : m01;
        float p10 = up ? o10 : m10, p11 = up ? o11 : m11;
        float q00 = up ? m00 : o00, q01 = up ? m01 : o01;
        float q10 = up ? m10 : o10, q11 = up ? m11 : o11;
        m00 = fmaf(p00, q00, p01 * q10);
        m01 = fmaf(p00, q01, p01 * q11);
        m10 = fmaf(p10, q00, p11 * q10);
        m11 = fmaf(p10, q01, p11 * q11);
        L += oL;
        gold += og;
    }

    if (lane == 0) {
        // total = L + log(sum of entries)   (alpha0 = zeros)
        float tot = L + __logf(m00 + m01 + m10 + m11);
        out[b]      = gold;   // gold_score
        out[Bn + b] = tot;    // total_score
    }
}

extern "C" void kernel_launch(void* const* d_in, const int* in_sizes, int n_in,
                              void* d_out, int out_size, void* d_ws, size_t ws_size,
                              hipStream_t stream) {
    const float* emissions    = (const float*)d_in[0];
    const float* trans_params = (const float*)d_in[1];
    const int*   tags         = (const int*)d_in[2];
    const int*   who2who      = (const int*)d_in[3];
    const int*   intime       = (const int*)d_in[4];
    const int*   distance     = (const int*)d_in[5];
    float* out = (float*)d_out;
    float4* ws = (float4*)d_ws;   // Bn*64*16B = 4 MB

    crf_stage<<<dim3(K1G), dim3(K1B), 0, stream>>>(
        emissions, trans_params, tags, who2who, intime, distance, ws);
    crf_final<<<dim3(Bn / 4), dim3(256), 0, stream>>>(ws, out);
}

// Round 12
// 191.561 us; speedup vs baseline: 1.0838x; 1.0506x over previous
//
#include <hip/hip_runtime.h>
#include <math.h>

// Problem constants (match reference setup_inputs)
#define Bn 4096
#define Sn 2048
#define NPAIR (Bn * (Sn / 2))        // 4,194,304 2-step pairs
#define K1B 256
#define K1G (NPAIR / K1B)            // 16384 blocks
#define NGRP 64                      // 32-step groups per sequence

// Native clang vector types: __builtin_nontemporal_* requires these
// (HIP_vector_type is a struct and is rejected -- R11 compile failure).
typedef float vfloat4 __attribute__((ext_vector_type(4)));
typedef int   vint2   __attribute__((ext_vector_type(2)));

// bf16 round-to-nearest pack of two floats: x -> low16, y -> high16
__device__ __forceinline__ unsigned pack_bf16(float x, float y) {
    unsigned bx = __float_as_uint(x);
    unsigned by = __float_as_uint(y);
    bx += 0x7FFFu + ((bx >> 16) & 1);
    by += 0x7FFFu + ((by >> 16) & 1);
    return (bx >> 16) | (by & 0xFFFF0000u);
}

// =====================================================================
// Kernel 1, Round 12: R9's validated kernel with NON-TEMPORAL streaming
// (retry of R11 with native vector types).
// R9 post-mortem arithmetic: 5.7 GB/s/CU delivered = ~3.4 KB in flight
// per CU -- consistent with a per-CU L1/TCP outstanding-miss cap; every
// round so far allocated all streams through L1. The input streams have
// ZERO reuse; nt loads bypass L1 allocation and use the deeper L2/TCC
// queues. Single-variable change vs R9 (71.8 us, absmax 8.0).
// =====================================================================
__global__ __launch_bounds__(K1B) void crf_stage(
    const float* __restrict__ emissions,     // [B, S, 2]
    const float* __restrict__ trans_params,  // [4, 2, 2]
    const int*   __restrict__ tags,          // [B, S]
    const int*   __restrict__ who2who,       // [B, S]
    const int*   __restrict__ intime,        // [B, S]
    const int*   __restrict__ distance,      // [B, S]
    float*       __restrict__ ws)            // [NPAIR/16 * 4] group records
{
    const int t    = blockIdx.x * K1B + threadIdx.x;  // global pair id
    const int lane = threadIdx.x & 63;
    const int j    = t & 1023;               // pair index within sequence

    // ---- dense coalesced NT loads (no L1 allocation, zero reuse) ----
    vfloat4 e  = __builtin_nontemporal_load(((const vfloat4*)emissions) + t);
    vint2   tg = __builtin_nontemporal_load(((const vint2*)tags)     + t);
    vint2   wh = __builtin_nontemporal_load(((const vint2*)who2who)  + t);
    vint2   i2 = __builtin_nontemporal_load(((const vint2*)intime)   + t);
    vint2   d2 = __builtin_nontemporal_load(((const vint2*)distance) + t);
    int ptag = 0;
    if (lane == 0 && j != 0) ptag = tags[2 * t - 1];  // cached (reuse-hot)

    // ---- transition rows from global (80B, permanently cache-hot) ----
    int sel0 = (wh.x == -1) ? -1 : (wh.x == 1) ? 0
             : (i2.x == 0) ? 1 : (d2.x == 0) ? 2 : 3;
    int sel1 = (wh.y == -1) ? -1 : (wh.y == 1) ? 0
             : (i2.y == 0) ? 1 : (d2.y == 0) ? 2 : 3;
    float4 T0 = ((const float4*)trans_params)[sel0 < 0 ? 0 : sel0];
    float4 T1 = ((const float4*)trans_params)[sel1 < 0 ? 0 : sel1];
    if (sel0 < 0) T0 = make_float4(0.f, 0.f, 0.f, 0.f);  // w==-1: zero row
    if (sel1 < 0) T1 = make_float4(0.f, 0.f, 0.f, 0.f);

    // ---- 2-step matrix, fused exp(tr+em) (linear domain; validated) ----
    float a00 = __expf(T0.x + e.x), a01 = __expf(T0.y + e.y);
    float a10 = __expf(T0.z + e.x), a11 = __expf(T0.w + e.y);
    float c00 = __expf(T1.x + e.z), c01 = __expf(T1.y + e.w);
    float c10 = __expf(T1.z + e.z), c11 = __expf(T1.w + e.w);
    float m00 = fmaf(a00, c00, a01 * c10);
    float m01 = fmaf(a00, c01, a01 * c11);
    float m10 = fmaf(a10, c00, a11 * c10);
    float m11 = fmaf(a10, c01, a11 * c11);

    // ---- gold partial (log domain; transitions owned by this pair) ----
    float gold = (tg.x ? e.y : e.x) + (tg.y ? e.w : e.z);
    int pt0 = __shfl_up(tg.y, 1);
    if (lane == 0) pt0 = ptag;
    if (j > 0)     // no transition at sequence start
        gold += pt0 ? (tg.x ? T0.w : T0.z) : (tg.x ? T0.y : T0.x);
    gold += tg.x ? (tg.y ? T1.w : T1.z) : (tg.y ? T1.y : T1.x);

    // ---- normalize; 4-round ordered butterfly -> 32-step group ----
    float mx  = fmaxf(fmaxf(m00, m01), fmaxf(m10, m11));
    float inv = 1.0f / mx;
    float L   = __logf(mx);
    m00 *= inv; m01 *= inv; m10 *= inv; m11 *= inv;

    #pragma unroll
    for (int m = 1; m < 16; m <<= 1) {   // growth <= 2^4 (no renorm needed)
        float o00 = __shfl_xor(m00, m);
        float o01 = __shfl_xor(m01, m);
        float o10 = __shfl_xor(m10, m);
        float o11 = __shfl_xor(m11, m);
        float oL  = __shfl_xor(L, m);
        float og  = __shfl_xor(gold, m);
        bool up = (lane & m) != 0;
        float p00 = up ? o00 : m00, p01 = up ? o01 : m01;
        float p10 = up ? o10 : m10, p11 = up ? o11 : m11;
        float q00 = up ? m00 : o00, q01 = up ? m01 : o01;
        float q10 = up ? m10 : o10, q11 = up ? m11 : o11;
        m00 = fmaf(p00, q00, p01 * q10);
        m01 = fmaf(p00, q01, p01 * q11);
        m10 = fmaf(p10, q00, p11 * q10);
        m11 = fmaf(p10, q01, p11 * q11);
        L += oL;
        gold += og;
    }

    // ---- group leader stores 16B record (4 leaders/wave, 64B burst) ----
    if ((lane & 15) == 0) {
        float mx2  = fmaxf(fmaxf(m00, m01), fmaxf(m10, m11));
        float inv2 = 1.0f / mx2;
        L += __logf(mx2);
        unsigned u01 = pack_bf16(m00 * inv2, m01 * inv2);
        unsigned u23 = pack_bf16(m10 * inv2, m11 * inv2);
        vfloat4 rec;
        rec.x = __uint_as_float(u01);
        rec.y = __uint_as_float(u23);
        rec.z = L;
        rec.w = gold;
        __builtin_nontemporal_store(rec, ((vfloat4*)ws) + (t >> 4));
    }
}

// =====================================================================
// Kernel 2: one wave per sequence; 64 group records -> outputs.
// =====================================================================
__global__ __launch_bounds__(256) void crf_final(
    const float4* __restrict__ ws,
    float*        __restrict__ out)          // [2, B]
{
    const int lane = threadIdx.x & 63;
    const int b    = blockIdx.x * 4 + (threadIdx.x >> 6);

    float4 r = ws[b * NGRP + lane];
    unsigned u01 = __float_as_uint(r.x), u23 = __float_as_uint(r.y);
    float m00 = __uint_as_float(u01 << 16);
    float m01 = __uint_as_float(u01 & 0xFFFF0000u);
    float m10 = __uint_as_float(u23 << 16);
    float m11 = __uint_as_float(u23 & 0xFFFF0000u);
    float L = r.z, gold = r.w;

    #pragma unroll
    for (int m = 1; m < 64; m <<= 1) {   // normalized inputs: growth <= 64
        float o00 = __shfl_xor(m00, m);
        float o01 = __shfl_xor(m01, m);
        float o10 = __shfl_xor(m10, m);
        float o11 = __shfl_xor(m11, m);
        float oL  = __shfl_xor(L, m);
        float og  = __shfl_xor(gold, m);
        bool up = (lane & m) != 0;
        float p00 = up ? o00 : m00, p01 = up ? o01 : m01;
        float p10 = up ? o10 : m10, p11 = up ? o11 : m11;
        float q00 = up ? m00 : o00, q01 = up ? m01 : o01;
        float q10 = up ? m10 : o10, q11 = up ? m11 : o11;
        m00 = fmaf(p00, q00, p01 * q10);
        m01 = fmaf(p00, q01, p01 * q11);
        m10 = fmaf(p10, q00, p11 * q10);
        m11 = fmaf(p10, q01, p11 * q11);
        L += oL;
        gold += og;
    }

    if (lane == 0) {
        // total = L + log(sum of entries)   (alpha0 = zeros)
        float tot = L + __logf(m00 + m01 + m10 + m11);
        out[b]      = gold;   // gold_score
        out[Bn + b] = tot;    // total_score
    }
}

extern "C" void kernel_launch(void* const* d_in, const int* in_sizes, int n_in,
                              void* d_out, int out_size, void* d_ws, size_t ws_size,
                              hipStream_t stream) {
    const float* emissions    = (const float*)d_in[0];
    const float* trans_params = (const float*)d_in[1];
    const int*   tags         = (const int*)d_in[2];
    const int*   who2who      = (const int*)d_in[3];
    const int*   intime       = (const int*)d_in[4];
    const int*   distance     = (const int*)d_in[5];
    float* out = (float*)d_out;
    float* ws = (float*)d_ws;   // NPAIR/16 * 16B = 4 MB

    crf_stage<<<dim3(K1G), dim3(K1B), 0, stream>>>(
        emissions, trans_params, tags, who2who, intime, distance, ws);
    crf_final<<<dim3(Bn / 4), dim3(256), 0, stream>>>((const float4*)ws, out);
}

// Round 13
// 189.038 us; speedup vs baseline: 1.0982x; 1.0133x over previous
//
#include <hip/hip_runtime.h>
#include <math.h>

// Problem constants (match reference setup_inputs)
#define Bn 4096
#define Sn 2048
#define NQUAD (Bn * (Sn / 4))        // 4-step quads: 2,097,152
#define K1B 256
#define K1G (NQUAD / K1B)            // 8192 blocks
#define NGRP 32                      // 64-step groups per sequence

// Native clang vector types (__builtin_nontemporal_* rejects HIP structs)
typedef float vfloat4 __attribute__((ext_vector_type(4)));
typedef int   vint4   __attribute__((ext_vector_type(4)));

// bf16 round-to-nearest pack of two floats: x -> low16, y -> high16
__device__ __forceinline__ unsigned pack_bf16(float x, float y) {
    unsigned bx = __float_as_uint(x);
    unsigned by = __float_as_uint(y);
    bx += 0x7FFFu + ((bx >> 16) & 1);
    by += 0x7FFFu + ((by >> 16) & 1);
    return (bx >> 16) | (by & 0xFFFF0000u);
}

// =====================================================================
// Kernel 1, Round 13: NT streaming (R12's confirmed win: L1 bypass
// lifted the 9-round 74us plateau -> 43us) + 4 steps/thread:
//  - each int array is ONE dense int4 NT load (2x bytes/wave in flight,
//    half the load instructions)
//  - 4-step matrix composed in-registers (3 matmuls, ZERO shuffles)
//    before the 4-round butterfly -> half the ds_bpermute work per byte
//  - workspace halves to 2 MB
// Math: validated linear-domain scan (absmax 8.0 since R2).
// 4-step product growth <= 8*e^24 ~ 2e11: fp32-safe before normalize.
// =====================================================================
__global__ __launch_bounds__(K1B) void crf_stage(
    const float* __restrict__ emissions,     // [B, S, 2]
    const float* __restrict__ trans_params,  // [4, 2, 2]
    const int*   __restrict__ tags,          // [B, S]
    const int*   __restrict__ who2who,       // [B, S]
    const int*   __restrict__ intime,        // [B, S]
    const int*   __restrict__ distance,      // [B, S]
    float*       __restrict__ ws)            // [NQUAD/16 * 4] group records
{
    const int T    = blockIdx.x * K1B + threadIdx.x;  // quad id
    const int lane = threadIdx.x & 63;
    const int jq   = T & 511;                // quad index within sequence

    // ---- dense NT loads: 2x float4 (em) + 4x int4 (flags) ----
    vfloat4 e0 = __builtin_nontemporal_load(((const vfloat4*)emissions) + 2 * T);
    vfloat4 e1 = __builtin_nontemporal_load(((const vfloat4*)emissions) + 2 * T + 1);
    vint4   tg = __builtin_nontemporal_load(((const vint4*)tags)     + T);
    vint4   wh = __builtin_nontemporal_load(((const vint4*)who2who)  + T);
    vint4   i2 = __builtin_nontemporal_load(((const vint4*)intime)   + T);
    vint4   d2 = __builtin_nontemporal_load(((const vint4*)distance) + T);
    int ptag = 0;
    if (lane == 0 && jq != 0) ptag = tags[4 * T - 1];  // cached (reuse-hot)

    // ---- transition rows from global (80B, permanently cache-hot) ----
    int s0 = (wh.x == -1) ? -1 : (wh.x == 1) ? 0
           : (i2.x == 0) ? 1 : (d2.x == 0) ? 2 : 3;
    int s1 = (wh.y == -1) ? -1 : (wh.y == 1) ? 0
           : (i2.y == 0) ? 1 : (d2.y == 0) ? 2 : 3;
    int s2 = (wh.z == -1) ? -1 : (wh.z == 1) ? 0
           : (i2.z == 0) ? 1 : (d2.z == 0) ? 2 : 3;
    int s3 = (wh.w == -1) ? -1 : (wh.w == 1) ? 0
           : (i2.w == 0) ? 1 : (d2.w == 0) ? 2 : 3;
    float4 R0 = ((const float4*)trans_params)[s0 < 0 ? 0 : s0];
    float4 R1 = ((const float4*)trans_params)[s1 < 0 ? 0 : s1];
    float4 R2 = ((const float4*)trans_params)[s2 < 0 ? 0 : s2];
    float4 R3 = ((const float4*)trans_params)[s3 < 0 ? 0 : s3];
    if (s0 < 0) R0 = make_float4(0.f, 0.f, 0.f, 0.f);  // w==-1: zero row
    if (s1 < 0) R1 = make_float4(0.f, 0.f, 0.f, 0.f);
    if (s2 < 0) R2 = make_float4(0.f, 0.f, 0.f, 0.f);
    if (s3 < 0) R3 = make_float4(0.f, 0.f, 0.f, 0.f);

    // ---- 4 step matrices, fused exp(tr+em) (linear domain) ----
    float a00 = __expf(R0.x + e0.x), a01 = __expf(R0.y + e0.y);
    float a10 = __expf(R0.z + e0.x), a11 = __expf(R0.w + e0.y);
    float b00 = __expf(R1.x + e0.z), b01 = __expf(R1.y + e0.w);
    float b10 = __expf(R1.z + e0.z), b11 = __expf(R1.w + e0.w);
    float c00 = __expf(R2.x + e1.x), c01 = __expf(R2.y + e1.y);
    float c10 = __expf(R2.z + e1.x), c11 = __expf(R2.w + e1.y);
    float d00 = __expf(R3.x + e1.z), d01 = __expf(R3.y + e1.w);
    float d10 = __expf(R3.z + e1.z), d11 = __expf(R3.w + e1.w);

    // ---- in-register 4-step compose: M = (S0*S1)*(S2*S3), no shuffles
    float p00 = fmaf(a00, b00, a01 * b10), p01 = fmaf(a00, b01, a01 * b11);
    float p10 = fmaf(a10, b00, a11 * b10), p11 = fmaf(a10, b01, a11 * b11);
    float q00 = fmaf(c00, d00, c01 * d10), q01 = fmaf(c00, d01, c01 * d11);
    float q10 = fmaf(c10, d00, c11 * d10), q11 = fmaf(c10, d01, c11 * d11);
    float m00 = fmaf(p00, q00, p01 * q10), m01 = fmaf(p00, q01, p01 * q11);
    float m10 = fmaf(p10, q00, p11 * q10), m11 = fmaf(p10, q01, p11 * q11);

    // ---- gold partial (log domain; 4 emissions + 4 owned transitions)
    float gold = (tg.x ? e0.y : e0.x) + (tg.y ? e0.w : e0.z)
               + (tg.z ? e1.y : e1.x) + (tg.w ? e1.w : e1.z);
    int pt = __shfl_up(tg.w, 1);             // quad T-1's last tag
    if (lane == 0) pt = ptag;
    if (jq != 0)                             // no transition at seq start
        gold += pt ? (tg.x ? R0.w : R0.z) : (tg.x ? R0.y : R0.x);
    gold += tg.x ? (tg.y ? R1.w : R1.z) : (tg.y ? R1.y : R1.x);
    gold += tg.y ? (tg.z ? R2.w : R2.z) : (tg.z ? R2.y : R2.x);
    gold += tg.z ? (tg.w ? R3.w : R3.z) : (tg.w ? R3.y : R3.x);

    // ---- normalize; 4-round ordered butterfly -> 64-step group ----
    float mx  = fmaxf(fmaxf(m00, m01), fmaxf(m10, m11));
    float inv = 1.0f / mx;
    float L   = __logf(mx);
    m00 *= inv; m01 *= inv; m10 *= inv; m11 *= inv;

    #pragma unroll
    for (int m = 1; m < 16; m <<= 1) {   // growth <= 2^4 (no renorm needed)
        float o00 = __shfl_xor(m00, m);
        float o01 = __shfl_xor(m01, m);
        float o10 = __shfl_xor(m10, m);
        float o11 = __shfl_xor(m11, m);
        float oL  = __shfl_xor(L, m);
        float og  = __shfl_xor(gold, m);
        bool up = (lane & m) != 0;
        float x00 = up ? o00 : m00, x01 = up ? o01 : m01;
        float x10 = up ? o10 : m10, x11 = up ? o11 : m11;
        float y00 = up ? m00 : o00, y01 = up ? m01 : o01;
        float y10 = up ? m10 : o10, y11 = up ? m11 : o11;
        m00 = fmaf(x00, y00, x01 * y10);
        m01 = fmaf(x00, y01, x01 * y11);
        m10 = fmaf(x10, y00, x11 * y10);
        m11 = fmaf(x10, y01, x11 * y11);
        L += oL;
        gold += og;
    }

    // ---- group leader stores 16B record (4 leaders/wave, 64B burst) ----
    if ((lane & 15) == 0) {
        float mx2  = fmaxf(fmaxf(m00, m01), fmaxf(m10, m11));
        float inv2 = 1.0f / mx2;
        L += __logf(mx2);
        unsigned u01 = pack_bf16(m00 * inv2, m01 * inv2);
        unsigned u23 = pack_bf16(m10 * inv2, m11 * inv2);
        vfloat4 rec;
        rec.x = __uint_as_float(u01);
        rec.y = __uint_as_float(u23);
        rec.z = L;
        rec.w = gold;
        __builtin_nontemporal_store(rec, ((vfloat4*)ws) + (T >> 4));
    }
}

// =====================================================================
// Kernel 2: one wave per sequence; 32 group records -> outputs.
// Lanes 0..31 hold real records (lanes 32+ duplicate, results unused);
// 5-round ordered butterfly stays within lanes 0..31 (masks 1..16).
// =====================================================================
__global__ __launch_bounds__(256) void crf_final(
    const float4* __restrict__ ws,
    float*        __restrict__ out)          // [2, B]
{
    const int lane = threadIdx.x & 63;
    const int b    = blockIdx.x * 4 + (threadIdx.x >> 6);

    float4 r = ws[b * NGRP + (lane & 31)];
    unsigned u01 = __float_as_uint(r.x), u23 = __float_as_uint(r.y);
    float m00 = __uint_as_float(u01 << 16);
    float m01 = __uint_as_float(u01 & 0xFFFF0000u);
    float m10 = __uint_as_float(u23 << 16);
    float m11 = __uint_as_float(u23 & 0xFFFF0000u);
    float L = r.z, gold = r.w;

    #pragma unroll
    for (int m = 1; m < 32; m <<= 1) {   // 5 rounds; lanes 0..31 self-contained
        float o00 = __shfl_xor(m00, m);
        float o01 = __shfl_xor(m01, m);
        float o10 = __shfl_xor(m10, m);
        float o11 = __shfl_xor(m11, m);
        float oL  = __shfl_xor(L, m);
        float og  = __shfl_xor(gold, m);
        bool up = (lane & m) != 0;
        float p00 = up ? o00 : m00, p01 = up ? o01 : m01;
        float p10 = up ? o10 : m10, p11 = up ? o11 : m11;
        float q00 = up ? m00 : o00, q01 = up ? m01 : o01;
        float q10 = up ? m10 : o10, q11 = up ? m11 : o11;
        m00 = fmaf(p00, q00, p01 * q10);
        m01 = fmaf(p00, q01, p01 * q11);
        m10 = fmaf(p10, q00, p11 * q10);
        m11 = fmaf(p10, q01, p11 * q11);
        L += oL;
        gold += og;
    }

    if (lane == 0) {
        // total = L + log(sum of entries)   (alpha0 = zeros)
        float tot = L + __logf(m00 + m01 + m10 + m11);
        out[b]      = gold;   // gold_score
        out[Bn + b] = tot;    // total_score
    }
}

extern "C" void kernel_launch(void* const* d_in, const int* in_sizes, int n_in,
                              void* d_out, int out_size, void* d_ws, size_t ws_size,
                              hipStream_t stream) {
    const float* emissions    = (const float*)d_in[0];
    const float* trans_params = (const float*)d_in[1];
    const int*   tags         = (const int*)d_in[2];
    const int*   who2who      = (const int*)d_in[3];
    const int*   intime       = (const int*)d_in[4];
    const int*   distance     = (const int*)d_in[5];
    float* out = (float*)d_out;
    float* ws = (float*)d_ws;   // NQUAD/16 * 16B = 2 MB

    crf_stage<<<dim3(K1G), dim3(K1B), 0, stream>>>(
        emissions, trans_params, tags, who2who, intime, distance, ws);
    crf_final<<<dim3(Bn / 4), dim3(256), 0, stream>>>((const float4*)ws, out);
}